// Round 2
// baseline (213.921 us; speedup 1.0000x reference)
//
#include <hip/hip_runtime.h>

// Polynomial second-order scan, DEGREE=2, CROSS=[(1,1)], N=5, T=1e6.
// Output layout (floats): Z[T] | J[T][5] | H[T][5][5]  => 31*T total.
//
// Strategy: chunked scan with warm-up (recurrence coefficient
// a_t = w2 + w3*h + w4*x is strongly contracting, |a|~0.3 typ; 128 warm-up
// steps give error factor ~e^-150, far below f32 ulp, so chunks are
// independent). CHUNK=8, WARM=128 => 17 steps/output row, ~125k threads.
//
// Store coalescing: chunk t>=1 owns rows [8t, 8t+8); every 4-row batch
// starts at r % 4 == 0 so the Z (r), J (5r) and H (25r) float offsets are
// all multiples of 4 => 16B-aligned float4 stores. 31 scalar stores/row
// -> 7.75 dwordx4/row (4x fewer memory requests). Chunk 0 (rows 1..7)
// plus the zero row 0 is handled scalar by tid 0.

constexpr int T_LEN = 1000000;
constexpr int CHUNK = 8;
constexpr int WARM  = 128;
constexpr int NCHUNK = T_LEN / CHUNK; // 125000; chunk 0 covers rows 1..7

__device__ __forceinline__ void step_update(
    float x, float& h, float (&J)[5], float (&Hm)[15],
    const float (&w)[5], const float (&dt)[5], const float (&q)[5])
{
    // powers: xp = [1, x, x^2/2], hp = [1, h, h^2/2]
    const float xp1 = x;
    const float xp2 = 0.5f * x * x;
    const float hp1 = h;
    const float hp2 = 0.5f * h * h;
    const float xh  = xp1 * hp1;

    // df_dh (linear-recurrence coefficient)
    const float a = w[2] + w[3] * hp1 + w[4] * xp1;
    // h_new
    const float hnew = w[0]*xp1 + w[1]*xp2 + w[2]*hp1 + w[3]*hp2 + w[4]*xh;

    // df_dw (b), V, H_ww_diag (g); f_hh = w3
    const float b[5] = { xp1*dt[0], xp2*dt[1], hp1*dt[2], hp2*dt[3], xh*dt[4] };
    const float V[5] = { 0.f, 0.f, dt[2], hp1*dt[3], xp1*dt[4] };
    const float g[5] = { xp1*q[0], xp2*q[1], hp1*q[2], hp2*q[3], xh*q[4] };
    const float fhh = w[3];

    // H update (OLD J, OLD H), symmetric upper triangle (15 entries)
    int idx = 0;
    #pragma unroll
    for (int i = 0; i < 5; ++i) {
        #pragma unroll
        for (int j = i; j < 5; ++j) {
            float v = (i == j) ? g[i] : 0.f;
            v += V[i] * J[j] + V[j] * J[i];
            v += fhh * (J[i] * J[j]);
            Hm[idx] = v + a * Hm[idx];
            ++idx;
        }
    }
    // J update (OLD J)
    #pragma unroll
    for (int i = 0; i < 5; ++i) J[i] = b[i] + a * J[i];
    h = hnew;
}

__device__ __forceinline__ void scalar_store_row(
    float* __restrict__ out, int r, float h,
    const float (&J)[5], const float (&Hm)[15])
{
    out[r] = h;
    float* Jr = out + T_LEN + r * 5;
    #pragma unroll
    for (int i = 0; i < 5; ++i) Jr[i] = J[i];
    float* Hr = out + 6 * T_LEN + r * 25;
    int idx = 0;
    #pragma unroll
    for (int i = 0; i < 5; ++i) {
        #pragma unroll
        for (int j = i; j < 5; ++j) {
            Hr[i * 5 + j] = Hm[idx];
            if (i != j) Hr[j * 5 + i] = Hm[idx];
            ++idx;
        }
    }
}

__global__ __launch_bounds__(256)
void poly_scan_kernel(const float* __restrict__ X,
                      const float* __restrict__ P,
                      float* __restrict__ out)
{
    const int tid = blockIdx.x * blockDim.x + threadIdx.x;
    if (tid >= NCHUNK) return;

    float w[5], dt[5], q[5];
    #pragma unroll
    for (int i = 0; i < 5; ++i) {
        const float wi = tanhf(P[i]);
        w[i]  = wi;
        dt[i] = 1.f - wi * wi;
        q[i]  = -2.f * wi * dt[i];
    }

    float h = 0.f;
    float J[5]  = {0.f, 0.f, 0.f, 0.f, 0.f};
    float Hm[15] = {0.f,0.f,0.f,0.f,0.f,0.f,0.f,0.f,0.f,
                    0.f,0.f,0.f,0.f,0.f,0.f};

    if (tid == 0) {
        // row 0: zero initial state (d_out is poisoned, must write)
        out[0] = 0.f;
        #pragma unroll
        for (int i = 0; i < 5; ++i)  out[T_LEN + i] = 0.f;
        #pragma unroll
        for (int i = 0; i < 25; ++i) out[6 * T_LEN + i] = 0.f;
        // rows 1..7, exact from the true initial state
        for (int r = 1; r < 8; ++r) {
            step_update(X[r - 1], h, J, Hm, w, dt, q);
            scalar_store_row(out, r, h, J, Hm);
        }
        return;
    }

    const int r0 = tid * CHUNK;            // multiple of 8
    int rs = r0 - WARM; if (rs < 1) rs = 1; // rs==1 => exact (zero state at row 0)

    // warm-up (discarded): after this loop, state == true state at row r0-1
    for (int r = rs; r < r0; ++r) {
        step_update(X[r - 1], h, J, Hm, w, dt, q);
    }

    float* __restrict__ Jbase = out + T_LEN;
    float* __restrict__ Hbase = out + 6 * T_LEN;

    #pragma unroll 1
    for (int bb = 0; bb < 2; ++bb) {
        const int rb = r0 + bb * 4;        // rb % 4 == 0 => 16B-aligned offsets
        float zbuf[4];
        float jbuf[20];
        float hbuf[100];
        #pragma unroll
        for (int k = 0; k < 4; ++k) {
            step_update(X[rb + k - 1], h, J, Hm, w, dt, q);
            zbuf[k] = h;
            #pragma unroll
            for (int i = 0; i < 5; ++i) jbuf[k * 5 + i] = J[i];
            int idx = 0;
            #pragma unroll
            for (int i = 0; i < 5; ++i) {
                #pragma unroll
                for (int j = i; j < 5; ++j) {
                    hbuf[k * 25 + i * 5 + j] = Hm[idx];
                    if (i != j) hbuf[k * 25 + j * 5 + i] = Hm[idx];
                    ++idx;
                }
            }
        }
        // vectorized aligned stores
        *reinterpret_cast<float4*>(out + rb) =
            make_float4(zbuf[0], zbuf[1], zbuf[2], zbuf[3]);
        float* Jr = Jbase + rb * 5;
        #pragma unroll
        for (int v = 0; v < 5; ++v) {
            reinterpret_cast<float4*>(Jr)[v] =
                make_float4(jbuf[4*v], jbuf[4*v+1], jbuf[4*v+2], jbuf[4*v+3]);
        }
        float* Hr = Hbase + rb * 25;
        #pragma unroll
        for (int v = 0; v < 25; ++v) {
            reinterpret_cast<float4*>(Hr)[v] =
                make_float4(hbuf[4*v], hbuf[4*v+1], hbuf[4*v+2], hbuf[4*v+3]);
        }
    }
}

extern "C" void kernel_launch(void* const* d_in, const int* in_sizes, int n_in,
                              void* d_out, int out_size, void* d_ws, size_t ws_size,
                              hipStream_t stream) {
    const float* X = (const float*)d_in[0];
    const float* P = (const float*)d_in[1];
    float* out = (float*)d_out;

    const int threads = 256;
    const int blocks = (NCHUNK + threads - 1) / threads;
    poly_scan_kernel<<<blocks, threads, 0, stream>>>(X, P, out);
}